// Round 12
// baseline (417.499 us; speedup 1.0000x reference)
//
#include <hip/hip_runtime.h>

// ---------------------------------------------------------------------------
// MAF forward log-prob, fully fused. D=45, H=256, NB=6, L=2, K=8, M=23.
// R14: R11 config (64-row, 2WG/CU — best: 277us) + spline/GEMM phase MERGE.
// Cycle model (R13 counters): VALU issue 57%/SIMD (spline ~30%, epi ~11%),
// MFMA 17% — spline phases (VALU-bound) and GEMM phases (load/MFMA-bound)
// were serialized by barriers. Now merged phases g=1..4: each wave runs a
// balanced slice of spline(g-1) (unit tables, inverse to its gemm np), then
// waves 0-6 run output-gemm(g) compute; joint barrier; epilogue. Spline
// leaves the serial path. Spline precedes acc-init (no acc+spline reg
// overlap); spline/gemm remain separate kernel-body calls (compile-safe
// shape per R11). Pair-granularity K-prefix pipeline unchanged.
// ---------------------------------------------------------------------------

typedef __bf16 bf16;
typedef __bf16 bf16x8 __attribute__((ext_vector_type(8)));
typedef float  f32x16 __attribute__((ext_vector_type(16)));

#define TAILF  13.815510557964274f      /* -log(1e-6) */
#define TAIL2  27.631021115928548f      /* 2*TAILF */
#define CMIN   0.027631021115928548f    /* 2*TAILF*1e-3 */
#define LOGZ   41.352233994210265f      /* 0.5*45*log(2*pi) */

// ---------------- workspace layout (bytes) ----------------
#define WS_W0M   0            /* bf16 [6][8 cg][4 kt][512]   196608 */
#define WS_WHM   196608       /* bf16 [12][8 cg][16 kt][512] 1572864 */
#define WS_WFM   1769472      /* bf16 [30][7 cg][16 kt][512] 3440640 */
#define WS_BEFF  5210112      /* f32  [6][256]   6144 */
#define WS_BFP   5216256      /* f32  [30][224]  26880 */
#define WS_WCC   5243136      /* f32  [6][256]   6144 */
#define WS_BHP   5249280      /* f32  [12][256]  12288 */
#define WS_NEED  5261568

#define N_W0  (6*256*64)        /* 98304   */
#define N_WH  (6*2*256*256)     /* 786432  */
#define N_WF  (6*5*224*256)     /* 1720320 */
#define N_PREP (N_W0 + N_WH + N_WF)

// ---- sorted-degree permutation of hidden units ----
__device__ __forceinline__ int s_deg(int s) {
    return (s < 216) ? (s / 6) : (36 + (s - 216) / 5);
}
__device__ __forceinline__ int s_orig(int s) {
    int d, rk;
    if (s < 216) { d = s / 6; rk = s - d * 6; }
    else { int u = s - 216; d = 36 + u / 5; rk = u - (u / 5) * 5; }
    return d + 44 * rk;
}

// ---------------- merged prep kernel (mask + permute + cast + pack) --------
__global__ void prep_all(const float* __restrict__ W0, const float* __restrict__ b0,
                         const float* __restrict__ Wc, const float* __restrict__ bc,
                         const float* __restrict__ Wh, const float* __restrict__ Wf,
                         const float* __restrict__ bfv, const float* __restrict__ bh,
                         bf16* __restrict__ W0m, bf16* __restrict__ Whm,
                         bf16* __restrict__ Wfm,
                         float* __restrict__ beff, float* __restrict__ bfp,
                         float* __restrict__ Wcc, float* __restrict__ bhp)
{
    int idx = blockIdx.x * 256 + threadIdx.x;
    if (idx < N_W0) {
        int j = idx & 7, lane = (idx >> 3) & 63, chunk = idx >> 9;
        int kt = chunk & 3, cg = (chunk >> 2) & 7, b = chunk >> 5;
        int col = cg * 32 + (lane & 31);               // sorted hidden pos
        int k   = kt * 16 + (lane >> 5) * 8 + j;
        int o   = s_orig(col);
        float v = 0.f;
        if (k < 45 && s_deg(col) >= k)                 // m0: deg_h >= k+1
            v = W0[(b * 256 + o) * 45 + k];
        W0m[idx] = (bf16)v;
        if (k == 0) {
            beff[b * 256 + col] = b0[b * 256 + o] + bc[b * 256 + o];
            Wcc[b * 256 + col]  = Wc[b * 256 + o];
        }
    } else if (idx < N_W0 + N_WH) {
        int id = idx - N_W0;
        int j = id & 7, lane = (id >> 3) & 63, chunk = id >> 9;
        int kt = chunk & 15, cg = (chunk >> 4) & 7, bl = chunk >> 7;  // bl=b*2+l
        int col = cg * 32 + (lane & 31);
        int k   = kt * 16 + (lane >> 5) * 8 + j;
        int oc  = s_orig(col), ok = s_orig(k);
        float v = (s_deg(col) >= s_deg(k)) ? Wh[bl * 65536 + oc * 256 + ok] : 0.f;
        Whm[id] = (bf16)v;
        if (k == 0)
            bhp[bl * 256 + col] = bh[bl * 256 + oc];
    } else if (idx < N_PREP) {
        int id = idx - (N_W0 + N_WH);
        int j = id & 7, lane = (id >> 3) & 63, chunk = id >> 9;
        int kt = chunk & 15, t2 = chunk >> 4;
        int cg = t2 % 7, bg = t2 / 7;                  // bg = b*5+g
        int b  = bg / 5, g = bg - 5 * b;
        int col = cg * 32 + (lane & 31);               // 0..223 (param col)
        int k   = kt * 16 + (lane >> 5) * 8 + j;
        int ok  = s_orig(k);
        int f   = 9 * g + col / 23;
        int m   = col - (col / 23) * 23;
        bool valid = (col < 207);
        float v = 0.f;
        if (valid && (f > s_deg(k)))                   // mf strict
            v = Wf[(b * 1035 + f * 23 + m) * 256 + ok];
        Wfm[id] = (bf16)v;
        if (k == 0)
            bfp[bg * 224 + col] = valid ? bfv[b * 1035 + f * 23 + m] : 0.f;
    }
}

// ---------------- fused main kernel ----------------
// LDS (dynamic, 81040 B -> 2 blocks/CU):
#define SO_ZF    0        /* float [64][46]          11776 */
#define SO_ZB    11776    /* bf16  [64][56]           7168 */
#define SO_HIDA  18944    /* bf16  [64][264]         33792 */
#define SO_PBUF  52736    /* bf16  9 x 1544 (fl-major, 24/row + 8 skew) 27792 */
#define SO_COND  80528    /* float [64] */
#define SO_LD    80784    /* float [64] */
#define SMEM_BYTES 81040

#define PBF 1544          /* elements per feature slab: 64*24 + 8 skew */

// Chunk-PAIR counts per wave (np = ceil(real_prefix_chunks / 2)).
__constant__ unsigned char IN_NP[8]     = {1,1,1,1,1,1,2,2};
__constant__ unsigned char HID_NP[8]    = {2,3,3,5,6,6,8,8};
__constant__ unsigned char OUT_NP[5][7] = {
    {1,1,1,1,2,2,2},
    {2,3,3,3,3,4,4},
    {4,4,5,5,5,5,5},
    {6,6,6,6,7,7,7},
    {7,8,8,8,8,8,8}};

// Spline unit tables. A "unit" u = 64 tasks = feature u (all 64 rows, one
// per lane). Row i (i=0..3) = merged phase g=i+1 carrying spline group i;
// row 4 = bare spline group 4. Units sized inversely to the wave's gemm np.
__constant__ unsigned char SPL_START[5][8] = {
    {0,2,3,4,5,6,0,7},
    {0,1,2,3,4,5,0,6},
    {0,1,2,3,4,5,0,6},
    {0,2,3,4,5,0,0,6},
    {0,2,3,4,5,6,7,8}};
__constant__ unsigned char SPL_CNT[5][8] = {
    {2,1,1,1,1,1,0,2},
    {1,1,1,1,1,1,0,3},
    {1,1,1,1,1,1,0,3},
    {2,1,1,1,1,0,0,3},
    {2,1,1,1,1,1,1,1}};

// Epilogue for one 32x32 accumulator. C/D: col=lane&31, row=(r&3)+8*(r>>2)+4*(lane>>5).
// MODE 0: +bias+cond*wcol -> hidA; MODE 1: +bias, relu -> hidA;
// MODE 2: +bias -> pbuf (per-feature slab layout).
template<int MODE>
__device__ __forceinline__ void epi32(const f32x16& acc, int cg, int hf,
    const float* __restrict__ bias, const float* __restrict__ wcol,
    const float* condl, bf16* dst, int l31, int kh8)
{
    const int col = cg * 32 + l31;
    if (MODE == 2 && col >= 207) return;
    const float bv = bias[col];
    const int rb = (kh8 >> 1) + hf * 32;    // 4*(lane>>5) + half*32
    if (MODE == 2) {
        const int fl = col / 23, m = col - fl * 23;
        bf16* dp = dst + fl * PBF + m;
        #pragma unroll
        for (int r = 0; r < 16; ++r) {
            int row = (r & 3) + 8 * (r >> 2) + rb;
            dp[row * 24] = (bf16)(acc[r] + bv);
        }
    } else {
        const float wcv = (MODE == 0) ? wcol[col] : 0.f;
        #pragma unroll
        for (int r = 0; r < 16; ++r) {
            int row = (r & 3) + 8 * (r >> 2) + rb;
            float v = acc[r] + bv;
            if (MODE == 0) v += condl[row] * wcv;
            if (MODE == 1) v = fmaxf(v, 0.f);
            dst[row * 264 + col] = (bf16)v;
        }
    }
}

// GEMM compute only (no barriers, no epilogue): one cg per wave, both
// row-halves share each 1KB B-chunk. np = chunk PAIRS (wave-uniform, >=1).
// Rolled pipeline, prefetch distance three pairs.
template<int KTFULL>
__device__ __forceinline__ void gemm_compute(
    const bf16* Asrc, const int lda, const bf16* __restrict__ Wp,
    int cg, int np, int lane, f32x16& acc0, f32x16& acc1)
{
    const int l31 = lane & 31;
    const int kh8 = (lane >> 5) * 8;
    const bf16* Bp  = Wp + (size_t)cg * (KTFULL * 512) + lane * 8;
    const bf16* Alo = Asrc + l31 * lda + kh8;
    const bf16* Ahi = Alo + 32 * lda;

    acc0 = (f32x16){};
    acc1 = (f32x16){};
    bf16x8 rA0, rA1, rB0, rB1, rC0, rC1;

#define LB(c)  (*reinterpret_cast<const bf16x8*>(Bp + (size_t)(c) * 512))
#define LAL(c) (*reinterpret_cast<const bf16x8*>(Alo + (c) * 16))
#define LAH(c) (*reinterpret_cast<const bf16x8*>(Ahi + (c) * 16))
#define CHUNK(breg, c) { \
    bf16x8 a0_ = LAL(c), a1_ = LAH(c); \
    acc0 = __builtin_amdgcn_mfma_f32_32x32x16_bf16(a0_, breg, acc0, 0, 0, 0); \
    acc1 = __builtin_amdgcn_mfma_f32_32x32x16_bf16(a1_, breg, acc1, 0, 0, 0); }
#define LP(r0, r1, p) { r0 = LB(2*(p)); r1 = LB(2*(p)+1); }
#define CP(r0, r1, p) { CHUNK(r0, 2*(p)) CHUNK(r1, 2*(p)+1) }

    LP(rA0, rA1, 0);
    if (np > 1) LP(rB0, rB1, 1);
    if (np > 2) LP(rC0, rC1, 2);

    int p = 0;
    #pragma unroll 1
    while (p + 3 < np) {
        CP(rA0, rA1, p);
        LP(rA0, rA1, p + 3);
        CP(rB0, rB1, p + 1);
        if (p + 4 < np) LP(rB0, rB1, p + 4);
        CP(rC0, rC1, p + 2);
        if (p + 5 < np) LP(rC0, rC1, p + 5);
        p += 3;
    }
    CP(rA0, rA1, p);
    if (np - p > 1) CP(rB0, rB1, p + 1);
    if (np - p > 2) CP(rC0, rC1, p + 2);

#undef LB
#undef LAL
#undef LAH
#undef CHUNK
#undef LP
#undef CP
}

// One RQ-spline task: feature fb+fl, row r (= lane).
__device__ __forceinline__ void spline_task(int fb, int fl, int r,
    float* zf, bf16* zb, const bf16* pbuf, float& lad_acc)
{
    const bf16* pp = pbuf + fl * PBF + r * 24;
    bf16x8 q0 = *reinterpret_cast<const bf16x8*>(pp);
    bf16x8 q1 = *reinterpret_cast<const bf16x8*>(pp + 8);
    bf16x8 q2 = *reinterpret_cast<const bf16x8*>(pp + 16);
    float P[23];
    #pragma unroll
    for (int m = 0; m < 8; ++m) P[m]      = (float)q0[m];
    #pragma unroll
    for (int m = 0; m < 8; ++m) P[8 + m]  = (float)q1[m];
    #pragma unroll
    for (int m = 0; m < 7; ++m) P[16 + m] = (float)q2[m];

    float xin = zf[r * 46 + fb + fl];
    float xc  = fminf(fmaxf(xin, -TAILF), TAILF);
    bool inside = (xin >= -TAILF) && (xin <= TAILF);

    float mw = P[0];
    #pragma unroll
    for (int i = 1; i < 8; ++i) mw = fmaxf(mw, P[i]);
    float ew[8], sw = 0.f;
    #pragma unroll
    for (int i = 0; i < 8; ++i) { ew[i] = __expf((P[i] - mw) * 0.0625f); sw += ew[i]; }
    float rws = TAIL2 * 0.992f / sw;
    float cw[9], wb[8];
    cw[0] = -TAILF;
    #pragma unroll
    for (int i = 0; i < 8; ++i) {
        wb[i] = fmaf(ew[i], rws, CMIN);
        cw[i + 1] = cw[i] + wb[i];
    }
    cw[8] = TAILF;
    wb[7] = TAILF - cw[7];

    float mh = P[8];
    #pragma unroll
    for (int i = 1; i < 8; ++i) mh = fmaxf(mh, P[8 + i]);
    float eh[8], sh = 0.f;
    #pragma unroll
    for (int i = 0; i < 8; ++i) { eh[i] = __expf((P[8 + i] - mh) * 0.0625f); sh += eh[i]; }
    float rhs = TAIL2 * 0.992f / sh;
    float ch[9], hb[8];
    ch[0] = -TAILF;
    #pragma unroll
    for (int i = 0; i < 8; ++i) {
        hb[i] = fmaf(eh[i], rhs, CMIN);
        ch[i + 1] = ch[i] + hb[i];
    }
    ch[8] = TAILF;
    hb[7] = TAILF - ch[7];

    float dd[9];
    dd[0] = 1.0f; dd[8] = 1.0f;
    #pragma unroll
    for (int i = 1; i < 8; ++i)
        dd[i] = 1e-3f + __logf(1.f + __expf(P[15 + i]));

    float icw = cw[0], ich = ch[0], ibw = wb[0], ibh = hb[0];
    float id0 = dd[0], id1 = dd[1];
    #pragma unroll
    for (int i = 1; i < 8; ++i) {
        bool ge = xc >= cw[i];
        icw = ge ? cw[i] : icw;  ich = ge ? ch[i] : ich;
        ibw = ge ? wb[i] : ibw;  ibh = ge ? hb[i] : ibh;
        id0 = ge ? dd[i] : id0;  id1 = ge ? dd[i + 1] : id1;
    }

    float th  = (xc - icw) / ibw;
    float th1 = th * (1.f - th);
    float dl  = ibh / ibw;
    float den = dl + (id0 + id1 - 2.f * dl) * th1;
    float yy  = ich + ibh * (dl * th * th + id0 * th1) / den;
    float num = dl * dl * (id1 * th * th + 2.f * dl * th1
                           + id0 * (1.f - th) * (1.f - th));
    float lad = __logf(num) - 2.f * __logf(den);

    if (inside) {
        zf[r * 46 + fb + fl] = yy;
        zb[r * 56 + fb + fl] = (bf16)yy;
    }
    lad_acc += inside ? lad : 0.f;
}

// Run this wave's unit slice of spline group (fb/9): units [start, start+cnt).
__device__ __forceinline__ void spline_units(int fb, int start, int cnt,
    float* zf, bf16* zb, const bf16* pbuf, int lane, float& lad_acc)
{
    #pragma unroll 1
    for (int k = 0; k < cnt; ++k)
        spline_task(fb, start + k, lane, zf, zb, pbuf, lad_acc);
}

__global__ __launch_bounds__(512, 2) void maf_main(
    const float* __restrict__ x, const float* __restrict__ cond,
    const bf16* __restrict__ W0m, const bf16* __restrict__ Whm,
    const bf16* __restrict__ Wfm,
    const float* __restrict__ beff, const float* __restrict__ bfp,
    const float* __restrict__ Wcc, const float* __restrict__ bhp,
    float* __restrict__ out, int B)
{
    extern __shared__ char smem[];
    float* zf    = (float*)(smem + SO_ZF);
    bf16*  zb    = (bf16*)(smem + SO_ZB);
    bf16*  hidA  = (bf16*)(smem + SO_HIDA);
    bf16*  pbuf  = (bf16*)(smem + SO_PBUF);
    float* condl = (float*)(smem + SO_COND);
    float* ldl   = (float*)(smem + SO_LD);

    const int t    = threadIdx.x;
    const int r0   = blockIdx.x * 64;
    const int w    = t >> 6;
    const int lane = t & 63;
    const int wu   = __builtin_amdgcn_readfirstlane(w);
    const int l31  = lane & 31;
    const int kh8  = (lane >> 5) * 8;

    for (int i = t; i < 64 * 11; i += 512) {
        int r = i / 11, c = i - (i / 11) * 11;
        zb[r * 56 + 45 + c] = (bf16)0.f;
    }
    if (t < 8) hidA[t] = (bf16)0.f;   // zb row63 chunk-3 hi-half overreads here
    for (int i = t; i < 64 * 45; i += 512) {
        int r = i / 45, f = i - (i / 45) * 45;
        float v = (r0 + r < B) ? x[(size_t)(r0 + r) * 45 + f] : 0.f;
        zf[r * 46 + f] = v;
        zb[r * 56 + f] = (bf16)v;
    }
    if (t < 64) {
        condl[t] = (r0 + t < B) ? cond[r0 + t] : 0.f;
        ldl[t]   = 0.f;
    }
    __syncthreads();

    float lad_acc = 0.f;

    const int inNp  = IN_NP[wu];
    const int hidNp = HID_NP[wu];
    const int ocg0  = (wu <= 5) ? wu : 6;                 // g0 col-group

    #pragma unroll 1
    for (int b = 0; b < 6; ++b) {
        f32x16 a0, a1;
        // ---- input MADE layer: +cond*Wc + (b0+bc) ----
        gemm_compute<4>(zb, 56, W0m + b * 16384, wu, inNp, lane, a0, a1);
        epi32<0>(a0, wu, 0, beff + b * 256, Wcc + b * 256, condl, hidA, l31, kh8);
        epi32<0>(a1, wu, 1, beff + b * 256, Wcc + b * 256, condl, hidA, l31, kh8);
        __syncthreads();
        // ---- 2 hidden layers, relu, in-place ----
        #pragma unroll 1
        for (int l = 0; l < 2; ++l) {
            gemm_compute<16>(hidA, 264, Whm + (b * 2 + l) * 65536,
                             wu, hidNp, lane, a0, a1);
            __syncthreads();                 // all hidA reads done
            epi32<1>(a0, wu, 0, bhp + (b * 2 + l) * 256, nullptr, condl, hidA, l31, kh8);
            epi32<1>(a1, wu, 1, bhp + (b * 2 + l) * 256, nullptr, condl, hidA, l31, kh8);
            __syncthreads();
        }
        // ---- output group 0 (unmerged; waves 6,7 split cg6 halves) ----
        gemm_compute<16>(hidA, 264, Wfm + (size_t)(b * 5) * 57344,
                         ocg0, OUT_NP[0][ocg0], lane, a0, a1);
        if (wu <= 5) {
            epi32<2>(a0, wu, 0, bfp + (b * 5) * 224, nullptr, condl, pbuf, l31, kh8);
            epi32<2>(a1, wu, 1, bfp + (b * 5) * 224, nullptr, condl, pbuf, l31, kh8);
        } else if (wu == 6) {
            epi32<2>(a0, 6, 0, bfp + (b * 5) * 224, nullptr, condl, pbuf, l31, kh8);
        } else {
            epi32<2>(a1, 6, 1, bfp + (b * 5) * 224, nullptr, condl, pbuf, l31, kh8);
        }
        __syncthreads();                      // pbuf(0) ready
        // ---- merged phases g=1..4: spline(g-1) slice, then gemm(g) ----
        #pragma unroll 1
        for (int g = 1; g < 5; ++g) {
            spline_units((g - 1) * 9, SPL_START[g - 1][wu], SPL_CNT[g - 1][wu],
                         zf, zb, pbuf, lane, lad_acc);
            if (wu < 7)
                gemm_compute<16>(hidA, 264, Wfm + (size_t)(b * 5 + g) * 57344,
                                 wu, OUT_NP[g][wu], lane, a0, a1);
            __syncthreads();                  // spline pbuf-readers done
            if (wu < 7) {
                epi32<2>(a0, wu, 0, bfp + (b * 5 + g) * 224, nullptr, condl, pbuf, l31, kh8);
                epi32<2>(a1, wu, 1, bfp + (b * 5 + g) * 224, nullptr, condl, pbuf, l31, kh8);
            }
            __syncthreads();                  // pbuf(g) ready
        }
        // ---- bare spline for group 4 ----
        spline_units(36, SPL_START[4][wu], SPL_CNT[4][wu],
                     zf, zb, pbuf, lane, lad_acc);
        __syncthreads();                      // zb/zf ready for next block
    }

    atomicAdd(&ldl[t & 63], lad_acc);
    __syncthreads();

    if (t < 64 && r0 + t < B) {
        float s = 0.f;
        #pragma unroll
        for (int f = 0; f < 45; ++f) { float v = zf[t * 46 + f]; s += v * v; }
        out[r0 + t] = -0.5f * s - LOGZ + ldl[t];
    }
}

// ---------------- host entry ----------------
extern "C" void kernel_launch(void* const* d_in, const int* in_sizes, int n_in,
                              void* d_out, int out_size, void* d_ws, size_t ws_size,
                              hipStream_t stream)
{
    const float* x    = (const float*)d_in[0];
    const float* cond = (const float*)d_in[1];
    const float* W0   = (const float*)d_in[2];
    const float* b0   = (const float*)d_in[3];
    const float* Wc   = (const float*)d_in[4];
    const float* bc   = (const float*)d_in[5];
    const float* Wh   = (const float*)d_in[6];
    const float* bh   = (const float*)d_in[7];
    const float* Wf   = (const float*)d_in[8];
    const float* bfv  = (const float*)d_in[9];
    float* out = (float*)d_out;

    const int B = in_sizes[0] / 45;
    if (ws_size < (size_t)WS_NEED) return;   // fail loudly

    char* ws = (char*)d_ws;
    bf16*  W0m  = (bf16*)(ws + WS_W0M);
    bf16*  Whm  = (bf16*)(ws + WS_WHM);
    bf16*  Wfm  = (bf16*)(ws + WS_WFM);
    float* beff = (float*)(ws + WS_BEFF);
    float* bfp  = (float*)(ws + WS_BFP);
    float* Wcc  = (float*)(ws + WS_WCC);
    float* bhp  = (float*)(ws + WS_BHP);

    prep_all<<<(N_PREP + 255) / 256, 256, 0, stream>>>(
        W0, b0, Wc, bc, Wh, Wf, bfv, bh, W0m, Whm, Wfm, beff, bfp, Wcc, bhp);

    (void)hipFuncSetAttribute((const void*)maf_main,
                              hipFuncAttributeMaxDynamicSharedMemorySize,
                              SMEM_BYTES);

    const int nwg = (B + 63) / 64;
    maf_main<<<nwg, 512, SMEM_BYTES, stream>>>(
        x, cond, W0m, Whm, Wfm, beff, bfp, Wcc, bhp, out, B);
}

// Round 13
// 318.258 us; speedup vs baseline: 1.3118x; 1.3118x over previous
//
#include <hip/hip_runtime.h>

// ---------------------------------------------------------------------------
// MAF forward log-prob, fully fused. D=45, H=256, NB=6, L=2, K=8, M=23.
// R15: R11 (best: 277us steady) + micro-fixes only. Seven structural
// experiments (R12 32-row/4WG=335, R13 128-row/1WG=314, R14 merge=358) all
// regress vs the R5/R7/R11 shape -> structure frozen. Changes:
// (1) zf stride 46->47 floats (gcd(46,32)=2 gave 4-way bank conflicts on
// every spline zf access; 47 coprime with 32 -> conflict-free; +256B LDS,
// still 2 WGs/CU); (2) softmax max-subtraction removed (|P|/16 << 1, no
// overflow possible; -~30 VALU/task). Else identical to R11: 64-row WGs,
// pair-granularity K-prefixes, 3-pair-deep B prefetch, spline overlapped
// into next gemm via preEpiSync, __launch_bounds__(512,2).
// ---------------------------------------------------------------------------

typedef __bf16 bf16;
typedef __bf16 bf16x8 __attribute__((ext_vector_type(8)));
typedef float  f32x16 __attribute__((ext_vector_type(16)));

#define TAILF  13.815510557964274f      /* -log(1e-6) */
#define TAIL2  27.631021115928548f      /* 2*TAILF */
#define CMIN   0.027631021115928548f    /* 2*TAILF*1e-3 */
#define LOGZ   41.352233994210265f      /* 0.5*45*log(2*pi) */
#define ZFS    47                       /* zf row stride (floats), coprime 32 */

// ---------------- workspace layout (bytes) ----------------
#define WS_W0M   0            /* bf16 [6][8 cg][4 kt][512]   196608 */
#define WS_WHM   196608       /* bf16 [12][8 cg][16 kt][512] 1572864 */
#define WS_WFM   1769472      /* bf16 [30][7 cg][16 kt][512] 3440640 */
#define WS_BEFF  5210112      /* f32  [6][256]   6144 */
#define WS_BFP   5216256      /* f32  [30][224]  26880 */
#define WS_WCC   5243136      /* f32  [6][256]   6144 */
#define WS_BHP   5249280      /* f32  [12][256]  12288 */
#define WS_NEED  5261568

#define N_W0  (6*256*64)        /* 98304   */
#define N_WH  (6*2*256*256)     /* 786432  */
#define N_WF  (6*5*224*256)     /* 1720320 */
#define N_PREP (N_W0 + N_WH + N_WF)

// ---- sorted-degree permutation of hidden units ----
// orig degree-1 of unit k is k%44.  Sorted position s -> degree-1 s_deg(s),
// original index s_orig(s).  Degrees 0..35 have 6 copies, 36..43 have 5.
__device__ __forceinline__ int s_deg(int s) {
    return (s < 216) ? (s / 6) : (36 + (s - 216) / 5);
}
__device__ __forceinline__ int s_orig(int s) {
    int d, rk;
    if (s < 216) { d = s / 6; rk = s - d * 6; }
    else { int u = s - 216; d = 36 + u / 5; rk = u - (u / 5) * 5; }
    return d + 44 * rk;
}

// ---------------- merged prep kernel (mask + permute + cast + pack) --------
__global__ void prep_all(const float* __restrict__ W0, const float* __restrict__ b0,
                         const float* __restrict__ Wc, const float* __restrict__ bc,
                         const float* __restrict__ Wh, const float* __restrict__ Wf,
                         const float* __restrict__ bfv, const float* __restrict__ bh,
                         bf16* __restrict__ W0m, bf16* __restrict__ Whm,
                         bf16* __restrict__ Wfm,
                         float* __restrict__ beff, float* __restrict__ bfp,
                         float* __restrict__ Wcc, float* __restrict__ bhp)
{
    int idx = blockIdx.x * 256 + threadIdx.x;
    if (idx < N_W0) {
        int j = idx & 7, lane = (idx >> 3) & 63, chunk = idx >> 9;
        int kt = chunk & 3, cg = (chunk >> 2) & 7, b = chunk >> 5;
        int col = cg * 32 + (lane & 31);               // sorted hidden pos
        int k   = kt * 16 + (lane >> 5) * 8 + j;
        int o   = s_orig(col);
        float v = 0.f;
        if (k < 45 && s_deg(col) >= k)                 // m0: deg_h >= k+1
            v = W0[(b * 256 + o) * 45 + k];
        W0m[idx] = (bf16)v;
        if (k == 0) {
            beff[b * 256 + col] = b0[b * 256 + o] + bc[b * 256 + o];
            Wcc[b * 256 + col]  = Wc[b * 256 + o];
        }
    } else if (idx < N_W0 + N_WH) {
        int id = idx - N_W0;
        int j = id & 7, lane = (id >> 3) & 63, chunk = id >> 9;
        int kt = chunk & 15, cg = (chunk >> 4) & 7, bl = chunk >> 7;  // bl=b*2+l
        int col = cg * 32 + (lane & 31);
        int k   = kt * 16 + (lane >> 5) * 8 + j;
        int oc  = s_orig(col), ok = s_orig(k);
        float v = (s_deg(col) >= s_deg(k)) ? Wh[bl * 65536 + oc * 256 + ok] : 0.f;
        Whm[id] = (bf16)v;
        if (k == 0)
            bhp[bl * 256 + col] = bh[bl * 256 + oc];
    } else if (idx < N_PREP) {
        int id = idx - (N_W0 + N_WH);
        int j = id & 7, lane = (id >> 3) & 63, chunk = id >> 9;
        int kt = chunk & 15, t2 = chunk >> 4;
        int cg = t2 % 7, bg = t2 / 7;                  // bg = b*5+g
        int b  = bg / 5, g = bg - 5 * b;
        int col = cg * 32 + (lane & 31);               // 0..223 (param col)
        int k   = kt * 16 + (lane >> 5) * 8 + j;
        int ok  = s_orig(k);
        int f   = 9 * g + col / 23;
        int m   = col - (col / 23) * 23;
        bool valid = (col < 207);
        float v = 0.f;
        if (valid && (f > s_deg(k)))                   // mf strict
            v = Wf[(b * 1035 + f * 23 + m) * 256 + ok];
        Wfm[id] = (bf16)v;
        if (k == 0)
            bfp[bg * 224 + col] = valid ? bfv[b * 1035 + f * 23 + m] : 0.f;
    }
}

// ---------------- fused main kernel ----------------
// LDS (dynamic, 81296 B -> 2 blocks/CU):
#define SO_ZF    0        /* float [64][47]          12032 */
#define SO_ZB    12032    /* bf16  [64][56]           7168 */
#define SO_HIDA  19200    /* bf16  [64][264]         33792 */
#define SO_PBUF  52992    /* bf16  9 x 1544 (fl-major, 24/row + 8 skew) 27792 */
#define SO_COND  80784    /* float [64] */
#define SO_LD    81040    /* float [64] */
#define SMEM_BYTES 81296

#define PBF 1544          /* elements per feature slab: 64*24 + 8 skew */

// Chunk-PAIR counts per wave (np = ceil(real_prefix_chunks / 2)).
// Chunks beyond each mask prefix are zero in the packed buffers, so the
// rounding-up to a pair is numerically free.
__constant__ unsigned char IN_NP[8]     = {1,1,1,1,1,1,2,2};
__constant__ unsigned char HID_NP[8]    = {2,3,3,5,6,6,8,8};
__constant__ unsigned char OUT_NP[5][7] = {
    {1,1,1,1,2,2,2},
    {2,3,3,3,3,4,4},
    {4,4,5,5,5,5,5},
    {6,6,6,6,7,7,7},
    {7,8,8,8,8,8,8}};

// Epilogue for one 32x32 accumulator. C/D: col=lane&31, row=(r&3)+8*(r>>2)+4*(lane>>5).
// MODE 0: +bias+cond*wcol -> hidA; MODE 1: +bias, relu -> hidA;
// MODE 2: +bias -> pbuf (per-feature slab layout).
template<int MODE>
__device__ __forceinline__ void epi32(const f32x16& acc, int cg, int hf,
    const float* __restrict__ bias, const float* __restrict__ wcol,
    const float* condl, bf16* dst, int l31, int kh8)
{
    const int col = cg * 32 + l31;
    if (MODE == 2 && col >= 207) return;
    const float bv = bias[col];
    const int rb = (kh8 >> 1) + hf * 32;    // 4*(lane>>5) + half*32
    if (MODE == 2) {
        const int fl = col / 23, m = col - fl * 23;
        bf16* dp = dst + fl * PBF + m;
        #pragma unroll
        for (int r = 0; r < 16; ++r) {
            int row = (r & 3) + 8 * (r >> 2) + rb;
            dp[row * 24] = (bf16)(acc[r] + bv);
        }
    } else {
        const float wcv = (MODE == 0) ? wcol[col] : 0.f;
        #pragma unroll
        for (int r = 0; r < 16; ++r) {
            int row = (r & 3) + 8 * (r >> 2) + rb;
            float v = acc[r] + bv;
            if (MODE == 0) v += condl[row] * wcv;
            if (MODE == 1) v = fmaxf(v, 0.f);
            dst[row * 264 + col] = (bf16)v;
        }
    }
}

// GEMM: one cg per wave, BOTH row-halves (acc0 rows 0-31, acc1 rows 32-63)
// sharing each 1KB B-chunk. np = number of chunk PAIRS (wave-uniform, >=1).
// Rolled pipeline, prefetch distance THREE pairs (6 chunks / 6KB in flight):
// preload pairs 0,1,2; loop computes p,p+1,p+2 while loading p+3,p+4,p+5.
template<int KTFULL, int MODE>
__device__ __forceinline__ void gemm64(
    const bf16* Asrc, const int lda,
    const bf16* __restrict__ Wp,
    const float* __restrict__ bias, const float* __restrict__ wcol,
    const float* condl, bf16* dst,
    int cg, int np, int halfmask,
    int lane, bool preEpiSync)
{
    const int l31 = lane & 31;
    const int kh8 = (lane >> 5) * 8;
    const bf16* Bp  = Wp + (size_t)cg * (KTFULL * 512) + lane * 8;
    const bf16* Alo = Asrc + l31 * lda + kh8;
    const bf16* Ahi = Alo + 32 * lda;

    f32x16 acc0 = {}, acc1 = {};
    bf16x8 rA0, rA1, rB0, rB1, rC0, rC1;

#define LB(c)  (*reinterpret_cast<const bf16x8*>(Bp + (size_t)(c) * 512))
#define LAL(c) (*reinterpret_cast<const bf16x8*>(Alo + (c) * 16))
#define LAH(c) (*reinterpret_cast<const bf16x8*>(Ahi + (c) * 16))
#define CHUNK(breg, c) { \
    bf16x8 a0_ = LAL(c), a1_ = LAH(c); \
    acc0 = __builtin_amdgcn_mfma_f32_32x32x16_bf16(a0_, breg, acc0, 0, 0, 0); \
    acc1 = __builtin_amdgcn_mfma_f32_32x32x16_bf16(a1_, breg, acc1, 0, 0, 0); }
#define LP(r0, r1, p) { r0 = LB(2*(p)); r1 = LB(2*(p)+1); }
#define CP(r0, r1, p) { CHUNK(r0, 2*(p)) CHUNK(r1, 2*(p)+1) }

    LP(rA0, rA1, 0);
    if (np > 1) LP(rB0, rB1, 1);
    if (np > 2) LP(rC0, rC1, 2);

    int p = 0;
    #pragma unroll 1
    while (p + 3 < np) {
        CP(rA0, rA1, p);
        LP(rA0, rA1, p + 3);
        CP(rB0, rB1, p + 1);
        if (p + 4 < np) LP(rB0, rB1, p + 4);
        CP(rC0, rC1, p + 2);
        if (p + 5 < np) LP(rC0, rC1, p + 5);
        p += 3;
    }
    CP(rA0, rA1, p);
    if (np - p > 1) CP(rB0, rB1, p + 1);
    if (np - p > 2) CP(rC0, rC1, p + 2);

#undef LB
#undef LAL
#undef LAH
#undef CHUNK
#undef LP
#undef CP

    if (preEpiSync) __syncthreads();   // in-place layers / pbuf reader drain

    if (halfmask & 1) epi32<MODE>(acc0, cg, 0, bias, wcol, condl, dst, l31, kh8);
    if (halfmask & 2) epi32<MODE>(acc1, cg, 1, bias, wcol, condl, dst, l31, kh8);
    __syncthreads();
}

// RQ spline for 9 features starting at fb. Task map: fl = task>>6 (wave-
// uniform), r = task&63 -> fixed row per thread; log-det accumulates in reg.
// No max-subtraction in the softmaxes: |P|/16 << 1 for this network, so
// exp cannot overflow and the result matches the max-subtracted form to fp
// rounding. No barrier inside/after — pbuf is protected by the NEXT gemm's
// preEpiSync, and zf/zb cells are private to (row, feature).
__device__ __forceinline__ void do_spline9(int fb, float* zf, bf16* zb,
                                           const bf16* pbuf, int t, float& lad_acc)
{
    #pragma unroll 1
    for (int task = t; task < 576; task += 512) {
        int fl = task >> 6, r = task & 63;
        const bf16* pp = pbuf + fl * PBF + r * 24;
        bf16x8 q0 = *reinterpret_cast<const bf16x8*>(pp);
        bf16x8 q1 = *reinterpret_cast<const bf16x8*>(pp + 8);
        bf16x8 q2 = *reinterpret_cast<const bf16x8*>(pp + 16);
        float P[23];
        #pragma unroll
        for (int m = 0; m < 8; ++m) P[m]      = (float)q0[m];
        #pragma unroll
        for (int m = 0; m < 8; ++m) P[8 + m]  = (float)q1[m];
        #pragma unroll
        for (int m = 0; m < 7; ++m) P[16 + m] = (float)q2[m];

        float xin = zf[r * ZFS + fb + fl];
        float xc  = fminf(fmaxf(xin, -TAILF), TAILF);
        bool inside = (xin >= -TAILF) && (xin <= TAILF);

        float ew[8], sw = 0.f;
        #pragma unroll
        for (int i = 0; i < 8; ++i) { ew[i] = __expf(P[i] * 0.0625f); sw += ew[i]; }
        float rws = TAIL2 * 0.992f / sw;
        float cw[9], wb[8];
        cw[0] = -TAILF;
        #pragma unroll
        for (int i = 0; i < 8; ++i) {
            wb[i] = fmaf(ew[i], rws, CMIN);
            cw[i + 1] = cw[i] + wb[i];
        }
        cw[8] = TAILF;
        wb[7] = TAILF - cw[7];

        float eh[8], sh = 0.f;
        #pragma unroll
        for (int i = 0; i < 8; ++i) { eh[i] = __expf(P[8 + i] * 0.0625f); sh += eh[i]; }
        float rhs = TAIL2 * 0.992f / sh;
        float ch[9], hb[8];
        ch[0] = -TAILF;
        #pragma unroll
        for (int i = 0; i < 8; ++i) {
            hb[i] = fmaf(eh[i], rhs, CMIN);
            ch[i + 1] = ch[i] + hb[i];
        }
        ch[8] = TAILF;
        hb[7] = TAILF - ch[7];

        float dd[9];
        dd[0] = 1.0f; dd[8] = 1.0f;
        #pragma unroll
        for (int i = 1; i < 8; ++i)
            dd[i] = 1e-3f + __logf(1.f + __expf(P[15 + i]));

        float icw = cw[0], ich = ch[0], ibw = wb[0], ibh = hb[0];
        float id0 = dd[0], id1 = dd[1];
        #pragma unroll
        for (int i = 1; i < 8; ++i) {
            bool ge = xc >= cw[i];
            icw = ge ? cw[i] : icw;  ich = ge ? ch[i] : ich;
            ibw = ge ? wb[i] : ibw;  ibh = ge ? hb[i] : ibh;
            id0 = ge ? dd[i] : id0;  id1 = ge ? dd[i + 1] : id1;
        }

        float th  = (xc - icw) / ibw;
        float th1 = th * (1.f - th);
        float dl  = ibh / ibw;
        float den = dl + (id0 + id1 - 2.f * dl) * th1;
        float yy  = ich + ibh * (dl * th * th + id0 * th1) / den;
        float num = dl * dl * (id1 * th * th + 2.f * dl * th1
                               + id0 * (1.f - th) * (1.f - th));
        float lad = __logf(num) - 2.f * __logf(den);

        if (inside) {
            zf[r * ZFS + fb + fl] = yy;
            zb[r * 56 + fb + fl] = (bf16)yy;
        }
        lad_acc += inside ? lad : 0.f;
    }
}

__global__ __launch_bounds__(512, 2) void maf_main(
    const float* __restrict__ x, const float* __restrict__ cond,
    const bf16* __restrict__ W0m, const bf16* __restrict__ Whm,
    const bf16* __restrict__ Wfm,
    const float* __restrict__ beff, const float* __restrict__ bfp,
    const float* __restrict__ Wcc, const float* __restrict__ bhp,
    float* __restrict__ out, int B)
{
    extern __shared__ char smem[];
    float* zf    = (float*)(smem + SO_ZF);
    bf16*  zb    = (bf16*)(smem + SO_ZB);
    bf16*  hidA  = (bf16*)(smem + SO_HIDA);
    bf16*  pbuf  = (bf16*)(smem + SO_PBUF);
    float* condl = (float*)(smem + SO_COND);
    float* ldl   = (float*)(smem + SO_LD);

    const int t    = threadIdx.x;
    const int r0   = blockIdx.x * 64;
    const int w    = t >> 6;
    const int lane = t & 63;
    const int wu   = __builtin_amdgcn_readfirstlane(w);

    for (int i = t; i < 64 * 11; i += 512) {
        int r = i / 11, c = i - (i / 11) * 11;
        zb[r * 56 + 45 + c] = (bf16)0.f;
    }
    if (t < 8) hidA[t] = (bf16)0.f;   // zb row63 chunk-3 hi-half overreads here
    for (int i = t; i < 64 * 45; i += 512) {
        int r = i / 45, f = i - (i / 45) * 45;
        float v = (r0 + r < B) ? x[(size_t)(r0 + r) * 45 + f] : 0.f;
        zf[r * ZFS + f] = v;
        zb[r * 56 + f] = (bf16)v;
    }
    if (t < 64) {
        condl[t] = (r0 + t < B) ? cond[r0 + t] : 0.f;
        ldl[t]   = 0.f;
    }
    __syncthreads();

    float lad_acc = 0.f;

    const int inNp  = IN_NP[wu];
    const int hidNp = HID_NP[wu];
    const int ocg   = (wu <= 5) ? wu : 6;                 // output col-group
    const int ohm   = (wu <= 5) ? 3 : ((wu == 6) ? 1 : 2); // output halfmask

    #pragma unroll 1
    for (int b = 0; b < 6; ++b) {
        // input MADE layer (per-cg K prefix), +cond*Wc + (b0+bc)
        gemm64<4, 0>(zb, 56, W0m + b * 16384,
                     beff + b * 256, Wcc + b * 256, condl,
                     hidA, wu, inNp, 3, lane, false);
        // 2 hidden layers, relu, in-place
        #pragma unroll 1
        for (int l = 0; l < 2; ++l)
            gemm64<16, 1>(hidA, 264, Whm + (b * 2 + l) * 65536,
                          bhp + (b * 2 + l) * 256, nullptr, condl,
                          hidA, wu, hidNp, 3, lane, true);
        // params: 5 groups x 9 features. Spline(g) runs right after gemm(g)'s
        // ending barrier; gemm(g+1)'s preEpiSync drains spline readers of pbuf
        // before its epilogue overwrites it (no standalone sync needed).
        #pragma unroll 1
        for (int g = 0; g < 5; ++g) {
            gemm64<16, 2>(hidA, 264, Wfm + (size_t)(b * 5 + g) * 57344,
                          bfp + (b * 5 + g) * 224, nullptr, condl,
                          pbuf, ocg, OUT_NP[g][ocg], ohm, lane, g > 0);
            do_spline9(g * 9, zf, zb, pbuf, t, lad_acc);
        }
        __syncthreads();   // zb/zf complete for next block's input gemm
    }

    atomicAdd(&ldl[t & 63], lad_acc);
    __syncthreads();

    if (t < 64 && r0 + t < B) {
        float s = 0.f;
        #pragma unroll
        for (int f = 0; f < 45; ++f) { float v = zf[t * ZFS + f]; s += v * v; }
        out[r0 + t] = -0.5f * s - LOGZ + ldl[t];
    }
}

// ---------------- host entry ----------------
extern "C" void kernel_launch(void* const* d_in, const int* in_sizes, int n_in,
                              void* d_out, int out_size, void* d_ws, size_t ws_size,
                              hipStream_t stream)
{
    const float* x    = (const float*)d_in[0];
    const float* cond = (const float*)d_in[1];
    const float* W0   = (const float*)d_in[2];
    const float* b0   = (const float*)d_in[3];
    const float* Wc   = (const float*)d_in[4];
    const float* bc   = (const float*)d_in[5];
    const float* Wh   = (const float*)d_in[6];
    const float* bh   = (const float*)d_in[7];
    const float* Wf   = (const float*)d_in[8];
    const float* bfv  = (const float*)d_in[9];
    float* out = (float*)d_out;

    const int B = in_sizes[0] / 45;
    if (ws_size < (size_t)WS_NEED) return;   // fail loudly

    char* ws = (char*)d_ws;
    bf16*  W0m  = (bf16*)(ws + WS_W0M);
    bf16*  Whm  = (bf16*)(ws + WS_WHM);
    bf16*  Wfm  = (bf16*)(ws + WS_WFM);
    float* beff = (float*)(ws + WS_BEFF);
    float* bfp  = (float*)(ws + WS_BFP);
    float* Wcc  = (float*)(ws + WS_WCC);
    float* bhp  = (float*)(ws + WS_BHP);

    prep_all<<<(N_PREP + 255) / 256, 256, 0, stream>>>(
        W0, b0, Wc, bc, Wh, Wf, bfv, bh, W0m, Whm, Wfm, beff, bfp, Wcc, bhp);

    (void)hipFuncSetAttribute((const void*)maf_main,
                              hipFuncAttributeMaxDynamicSharedMemorySize,
                              SMEM_BYTES);

    const int nwg = (B + 63) / 64;
    maf_main<<<nwg, 512, SMEM_BYTES, stream>>>(
        x, cond, W0m, Whm, Wfm, beff, bfp, Wcc, bhp, out, B);
}